// Round 9
// baseline (240.418 us; speedup 1.0000x reference)
//
#include <hip/hip_runtime.h>
#include <math.h>

#define NN 4096
#define DD 512
#define NC 10
#define NG 2

#define BM 256
#define BN 256
#define BK 32
#define NT (DD / BK)     // 16 K-tiles
#define NTILES 528       // 136 TT + 136 SS + 256 TS (= 8 * 66)

typedef __bf16 bf16x8 __attribute__((ext_vector_type(8)));
typedef __bf16 bf16x4 __attribute__((ext_vector_type(4)));
typedef float f32x4 __attribute__((ext_vector_type(4)));

__device__ __forceinline__ void load_lds16(const __bf16* g, __bf16* l) {
    __builtin_amdgcn_global_load_lds((const __attribute__((address_space(1))) void*)g,
                                     (__attribute__((address_space(3))) void*)l, 16, 0, 0);
}

__device__ __forceinline__ float agent_ld(const float* p) {
    return __hip_atomic_load(p, __ATOMIC_RELAXED, __HIP_MEMORY_SCOPE_AGENT);
}

// ---------------------------------------------------------------------------
// Kernel 1: fused fp32->bf16 convert + per-row squared norms (fp32 exact)
// + zeroing of the accumulator region. (unchanged from round 8)
// ---------------------------------------------------------------------------
__global__ void k_prep(const float* __restrict__ ft, const float* __restrict__ fs,
                       __bf16* __restrict__ at, __bf16* __restrict__ as_,
                       float* __restrict__ nt, float* __restrict__ ns,
                       float* __restrict__ zero_base) {
    if (blockIdx.x < 69) {
        int idx = blockIdx.x * 256 + threadIdx.x;
        if (idx < 17412) zero_base[idx] = 0.0f;
    }
    int wid  = threadIdx.x >> 6;
    int lane = threadIdx.x & 63;
    int r = blockIdx.x * 4 + wid;
    const float* src; __bf16* bdst; float* ndst; int row;
    if (r < NN) { src = ft; bdst = at;  ndst = nt; row = r; }
    else        { src = fs; bdst = as_; ndst = ns; row = r - NN; }
    const float4* p = (const float4*)(src + (size_t)row * DD);
    float s = 0.0f;
#pragma unroll
    for (int c = 0; c < 2; ++c) {
        float4 v = p[lane + 64 * c];
        s += v.x * v.x + v.y * v.y + v.z * v.z + v.w * v.w;
        bf16x4 b;
        b[0] = (__bf16)v.x; b[1] = (__bf16)v.y; b[2] = (__bf16)v.z; b[3] = (__bf16)v.w;
        *(bf16x4*)(bdst + (size_t)row * DD + (lane + 64 * c) * 4) = b;
    }
#pragma unroll
    for (int o = 32; o; o >>= 1) s += __shfl_xor(s, o);
    if (lane == 0) ndst[row] = s;
}

// ---------------------------------------------------------------------------
// Kernel 2: column sums + (last block) closed-form sigma -> invscale.
// (unchanged from round 8)
// ---------------------------------------------------------------------------
__global__ void k_colsums(const float* __restrict__ ft, const float* __restrict__ fs,
                          float* __restrict__ sumT, float* __restrict__ sumS,
                          const float* __restrict__ nt, const float* __restrict__ ns,
                          float* __restrict__ invscale, unsigned int* __restrict__ cnt) {
    int b = blockIdx.x;
    int mat = b & 1;
    int chunk = b >> 1;
    const float* src = mat ? fs : ft;
    float* dst = mat ? sumS : sumT;
    int r0 = chunk * 32;
    int c0 = threadIdx.x, c1 = threadIdx.x + 256;
    float a0 = 0.0f, a1 = 0.0f;
    for (int r = r0; r < r0 + 32; ++r) {
        a0 += src[(size_t)r * DD + c0];
        a1 += src[(size_t)r * DD + c1];
    }
    atomicAdd(&dst[c0], a0);
    atomicAdd(&dst[c1], a1);

    __shared__ int amLast;
    __threadfence();
    __syncthreads();
    if (threadIdx.x == 0) amLast = (atomicAdd(cnt, 1u) == 255u) ? 1 : 0;
    __syncthreads();
    if (!amLast) return;
    __threadfence();

    __shared__ float red[8];
    int tid = threadIdx.x;
    float s = 0.0f;
    for (int i = tid; i < NN; i += 256) s += nt[i] + ns[i];
    float d = 0.0f;
    for (int i = tid; i < DD; i += 256) d += agent_ld(&sumT[i]) * agent_ld(&sumS[i]);
#pragma unroll
    for (int o = 32; o; o >>= 1) { s += __shfl_xor(s, o); d += __shfl_xor(d, o); }
    int wid = tid >> 6, lane = tid & 63;
    if (lane == 0) { red[wid] = s; red[wid + 4] = d; }
    __syncthreads();
    if (tid == 0) {
        float S  = red[0] + red[1] + red[2] + red[3];
        float Dt = red[4] + red[5] + red[6] + red[7];
        float sigma = S / (float)NN - 2.0f * Dt / ((float)NN * (float)NN);
        invscale[0] = 1.0f / (2.0f * sigma);
    }
}

// ---------------------------------------------------------------------------
// Kernel 3: all three Grams, 256x256 tile (HK geometry), phase-split.
// Tiles: [0,136) TT triangle (bj>=bi), [136,272) SS triangle, [272,528) TS.
// XCD swizzle: swz = (bid&7)*66 + bid>>3 (528 = 8*66, bijective).
// 8 waves (2Mx4N), wave tile 128x64: af[8] x bf[4] -> acc[8][4], 32 MFMA/tile
// in TWO 16-MFMA phases (m-halves) with s_setprio around each cluster (T5).
// BK=32, double-buffered LDS (64 KB), stage for t+1 issued at phase-A start,
// single vmcnt(0)+barrier per tile.
// LDS per buffer: [kq=4][row=256][8] bf16 -> conflict-free ds_read_b128.
// Sym modes: element rule c>r -> row+col add; c==r -> row only; c<r -> skip.
// ---------------------------------------------------------------------------
__global__ __launch_bounds__(512, 2) void k_gram_all(
    const __bf16* __restrict__ T, const __bf16* __restrict__ S,
    const float* __restrict__ nt, const float* __restrict__ ns,
    const int* __restrict__ labels, const int* __restrict__ groups,
    const float* __restrict__ invscale_p,
    float* __restrict__ zTT, float* __restrict__ zSS, float* __restrict__ zTS) {

    __shared__ __bf16 As[2][4 * 256 * 8];
    __shared__ __bf16 Bs[2][4 * 256 * 8];

    int swz = ((int)blockIdx.x & 7) * 66 + ((int)blockIdx.x >> 3);
    int mode, bi, bj;
    if (swz < 272) {
        mode = (swz < 136) ? 0 : 1;
        int k = (swz < 136) ? swz : swz - 136;
        int t = 0;
        while (k >= 16 - t) { k -= 16 - t; ++t; }   // uniform, <=16 iters
        bi = t; bj = t + k;
    } else {
        mode = 2;
        int k = swz - 272;
        bi = k >> 4; bj = k & 15;
    }

    const __bf16* A = (mode == 1) ? S : T;
    const __bf16* B = (mode == 0) ? T : S;
    const float* nA = (mode == 1) ? ns : nt;
    const float* nB = (mode == 0) ? nt : ns;
    float* z0 = (mode == 0) ? zTT : ((mode == 1) ? zSS : zTS);
    float* z1 = zTS + NN;

    int tid = threadIdx.x;
    int i0 = bi * BM;
    int j0 = bj * BN;

    int lane = tid & 63, wid = tid >> 6;
    int wr = wid >> 2, wc = wid & 3;          // 2 x 4 wave grid
    int l15 = lane & 15, l4 = lane >> 4;

    // staging: per matrix, slots tid and tid+512; row = slot&255, kq = slot>>8
    const __bf16* gA = A + (size_t)(i0 + (tid & 255)) * DD + (tid >> 8) * 8;
    const __bf16* gB = B + (size_t)(j0 + (tid & 255)) * DD + (tid >> 8) * 8;

    f32x4 acc[8][4] = {};

#define STAGE(bb, tt)                                                          \
    do {                                                                       \
        int _k0 = (tt) * BK;                                                   \
        load_lds16(gA + _k0,      &As[(bb)][(size_t)tid * 8]);                 \
        load_lds16(gA + _k0 + 16, &As[(bb)][(size_t)(tid + 512) * 8]);         \
        load_lds16(gB + _k0,      &Bs[(bb)][(size_t)tid * 8]);                 \
        load_lds16(gB + _k0 + 16, &Bs[(bb)][(size_t)(tid + 512) * 8]);         \
    } while (0)

    STAGE(0, 0);
    asm volatile("s_waitcnt vmcnt(0)" ::: "memory");
    __builtin_amdgcn_s_barrier();
    __builtin_amdgcn_sched_barrier(0);

#pragma unroll
    for (int t = 0; t < NT; ++t) {
        int b = t & 1;
        // phase A: B frags + first m-half of A frags; issue next tile's stage
        bf16x8 bfr[4], af0[4], af1[4];
#pragma unroll
        for (int in = 0; in < 4; ++in)
            bfr[in] = *(const bf16x8*)&Bs[b][((size_t)l4 * 256 + wc * 64 + in * 16 + l15) * 8];
#pragma unroll
        for (int im = 0; im < 4; ++im)
            af0[im] = *(const bf16x8*)&As[b][((size_t)l4 * 256 + wr * 128 + im * 16 + l15) * 8];
        if (t + 1 < NT) STAGE(b ^ 1, t + 1);
        __builtin_amdgcn_s_setprio(1);
#pragma unroll
        for (int im = 0; im < 4; ++im)
#pragma unroll
            for (int in = 0; in < 4; ++in)
                acc[im][in] = __builtin_amdgcn_mfma_f32_16x16x32_bf16(af0[im], bfr[in], acc[im][in], 0, 0, 0);
        __builtin_amdgcn_s_setprio(0);
        // phase B: second m-half
#pragma unroll
        for (int im = 0; im < 4; ++im)
            af1[im] = *(const bf16x8*)&As[b][((size_t)l4 * 256 + wr * 128 + (im + 4) * 16 + l15) * 8];
        __builtin_amdgcn_s_setprio(1);
#pragma unroll
        for (int im = 0; im < 4; ++im)
#pragma unroll
            for (int in = 0; in < 4; ++in)
                acc[im + 4][in] = __builtin_amdgcn_mfma_f32_16x16x32_bf16(af1[im], bfr[in], acc[im + 4][in], 0, 0, 0);
        __builtin_amdgcn_s_setprio(0);
        // tile end: next tile resident before buffer flip
        asm volatile("s_waitcnt vmcnt(0)" ::: "memory");
        __builtin_amdgcn_s_barrier();
        __builtin_amdgcn_sched_barrier(0);
    }
#undef STAGE

    // epilogue: D = nA + nB - 2*dot -> exp -> predicate -> row/col sums
    float inv_scale = invscale_p[0];
    int ibase = i0 + wr * 128;
    int jbase = j0 + wc * 64;
    float nBv[4];
    int labBv[4], grpBv[4];
#pragma unroll
    for (int in = 0; in < 4; ++in) {
        int j = jbase + in * 16 + l15;
        nBv[in] = nB[j];
        labBv[in] = labels[j];
        grpBv[in] = groups[j];
    }
    float cs[4] = {0.0f, 0.0f, 0.0f, 0.0f};   // sym col sums (c > r)
#pragma unroll
    for (int im = 0; im < 8; ++im) {
#pragma unroll
        for (int j = 0; j < 4; ++j) {
            int row = ibase + im * 16 + l4 * 4 + j;
            float ni = nA[row];
            int li = labels[row];
            int gi = groups[row];
            float s0 = 0.0f, s1 = 0.0f;
#pragma unroll
            for (int in = 0; in < 4; ++in) {
                float d = ni + nBv[in] - 2.0f * acc[im][in][j];
                d = fmaxf(d, 1e-12f);
                float kv = __expf(-d * inv_scale);
                bool ok = (li == labBv[in]);
                if (mode == 1) ok = ok && (gi == grpBv[in]);
                if (mode == 2) {
                    s0 += (ok && grpBv[in] == 0) ? kv : 0.0f;
                    s1 += (ok && grpBv[in] == 1) ? kv : 0.0f;
                } else {
                    int c = jbase + in * 16 + l15;
                    s0     += (ok && c >= row) ? kv : 0.0f;
                    cs[in] += (ok && c >  row) ? kv : 0.0f;
                }
            }
#pragma unroll
            for (int o = 1; o < 16; o <<= 1) {
                s0 += __shfl_xor(s0, o);
                if (mode == 2) s1 += __shfl_xor(s1, o);
            }
            if (l15 == 0) {
                atomicAdd(&z0[row], s0);
                if (mode == 2) atomicAdd(&z1[row], s1);
            }
        }
    }
    if (mode != 2) {
#pragma unroll
        for (int in = 0; in < 4; ++in) {
            cs[in] += __shfl_xor(cs[in], 16);
            cs[in] += __shfl_xor(cs[in], 32);
        }
        if (l4 == 0) {
#pragma unroll
            for (int in = 0; in < 4; ++in)
                atomicAdd(&z0[jbase + in * 16 + l15], cs[in]);
        }
    }
}

// ---------------------------------------------------------------------------
// Kernel 4: bucket per-row sums, final scalar. (unchanged from round 8)
// ---------------------------------------------------------------------------
__global__ void k_final(const int* __restrict__ labels, const int* __restrict__ groups,
                        const float* __restrict__ zTT, const float* __restrict__ zSS,
                        const float* __restrict__ zTS, float* __restrict__ out) {
    __shared__ float cnt_t[NC], cnt_s[NC * NG];
    __shared__ float nTT[NC], nSS[NC * NG], nTS[NC * NG];
    int tid = threadIdx.x;
    if (tid < NC) { cnt_t[tid] = 0.0f; nTT[tid] = 0.0f; }
    if (tid < NC * NG) { cnt_s[tid] = 0.0f; nSS[tid] = 0.0f; nTS[tid] = 0.0f; }
    __syncthreads();
    for (int i = tid; i < NN; i += 256) {
        int l = labels[i], g = groups[i];
        atomicAdd(&cnt_t[l], 1.0f);
        atomicAdd(&cnt_s[l * NG + g], 1.0f);
        atomicAdd(&nTT[l], zTT[i]);
        atomicAdd(&nSS[l * NG + g], zSS[i]);
        atomicAdd(&nTS[l * NG + 0], zTS[i]);
        atomicAdd(&nTS[l * NG + 1], zTS[NN + i]);
    }
    __syncthreads();
    if (tid == 0) {
        float total = 0.0f;
        for (int c = 0; c < NC; ++c) {
            float ntc = cnt_t[c];
            float sn = fmaxf(ntc, 1.0f);
            float meanTT = nTT[c] / (sn * sn);
            for (int g = 0; g < NG; ++g) {
                float nsg = cnt_s[c * NG + g];
                float ss = fmaxf(nsg, 1.0f);
                float meanSS = nSS[c * NG + g] / (ss * ss);
                float meanTS = nTS[c * NG + g] / (sn * ss);
                if (ntc > 0.0f && nsg > 0.0f)
                    total += meanTT + meanSS - 2.0f * meanTS;
            }
        }
        out[0] = 0.5f * total;
    }
}

// ---------------------------------------------------------------------------
// workspace layout:
// bytes [0, 4MB)      : teacher bf16 [4096][512]
// bytes [4MB, 8MB)    : student bf16 [4096][512]
// floats from 8MB (wsf):
//   +0      nt[4096]
//   +4096   ns[4096]
//   +8192   sumT[512]      <- zero region start (17412 floats)
//   +8704   sumS[512]
//   +9216   zTT[4096]
//   +13312  zSS[4096]
//   +17408  zTS[2*4096]
//   +25600  invscale[1]
//   +25601  counter_colsums (uint)
//   +25602  (spare, zeroed)
// ---------------------------------------------------------------------------
extern "C" void kernel_launch(void* const* d_in, const int* in_sizes, int n_in,
                              void* d_out, int out_size, void* d_ws, size_t ws_size,
                              hipStream_t stream) {
    const float* fs     = (const float*)d_in[0];
    const float* ft     = (const float*)d_in[1];
    const int*   groups = (const int*)d_in[2];
    const int*   labels = (const int*)d_in[3];

    __bf16* Abf = (__bf16*)d_ws;                       // teacher
    __bf16* Bbf = (__bf16*)d_ws + (size_t)NN * DD;     // student
    float* wsf  = (float*)((char*)d_ws + (size_t)2 * NN * DD * sizeof(__bf16));
    float* nt   = wsf;
    float* ns   = wsf + 4096;
    float* sumT = wsf + 8192;
    float* sumS = wsf + 8704;
    float* zTT  = wsf + 9216;
    float* zSS  = wsf + 13312;
    float* zTS  = wsf + 17408;
    float* invs = wsf + 25600;
    unsigned int* cntC = (unsigned int*)(wsf + 25601);

    k_prep<<<2048, 256, 0, stream>>>(ft, fs, Abf, Bbf, nt, ns, wsf + 8192);
    k_colsums<<<256, 256, 0, stream>>>(ft, fs, sumT, sumS, nt, ns, invs, cntC);
    k_gram_all<<<NTILES, 512, 0, stream>>>(Abf, Bbf, nt, ns, labels, groups,
                                           invs, zTT, zSS, zTS);
    k_final<<<1, 256, 0, stream>>>(labels, groups, zTT, zSS, zTS, (float*)d_out);
}

// Round 10
// 212.881 us; speedup vs baseline: 1.1294x; 1.1294x over previous
//
#include <hip/hip_runtime.h>
#include <math.h>

#define NN 4096
#define DD 512
#define NC 10
#define NG 2

#define BM 256
#define BN 128
#define BK 32
#define NT (DD / BK)     // 16 K-steps
#define NTILES 1536      // full 3x(16x32) grid; 480 blocks early-exit (triangle)

typedef __bf16 bf16x8 __attribute__((ext_vector_type(8)));
typedef __bf16 bf16x4 __attribute__((ext_vector_type(4)));
typedef float f32x4 __attribute__((ext_vector_type(4)));

__device__ __forceinline__ void load_lds16(const __bf16* g, __bf16* l) {
    __builtin_amdgcn_global_load_lds((const __attribute__((address_space(1))) void*)g,
                                     (__attribute__((address_space(3))) void*)l, 16, 0, 0);
}

__device__ __forceinline__ float agent_ld(const float* p) {
    return __hip_atomic_load(p, __ATOMIC_RELAXED, __HIP_MEMORY_SCOPE_AGENT);
}

// ---------------------------------------------------------------------------
// Kernel 1: fused fp32->bf16 convert + per-row squared norms (fp32 exact)
// + zeroing of the accumulator region. (unchanged from round 8)
// ---------------------------------------------------------------------------
__global__ void k_prep(const float* __restrict__ ft, const float* __restrict__ fs,
                       __bf16* __restrict__ at, __bf16* __restrict__ as_,
                       float* __restrict__ nt, float* __restrict__ ns,
                       float* __restrict__ zero_base) {
    if (blockIdx.x < 69) {
        int idx = blockIdx.x * 256 + threadIdx.x;
        if (idx < 17412) zero_base[idx] = 0.0f;
    }
    int wid  = threadIdx.x >> 6;
    int lane = threadIdx.x & 63;
    int r = blockIdx.x * 4 + wid;
    const float* src; __bf16* bdst; float* ndst; int row;
    if (r < NN) { src = ft; bdst = at;  ndst = nt; row = r; }
    else        { src = fs; bdst = as_; ndst = ns; row = r - NN; }
    const float4* p = (const float4*)(src + (size_t)row * DD);
    float s = 0.0f;
#pragma unroll
    for (int c = 0; c < 2; ++c) {
        float4 v = p[lane + 64 * c];
        s += v.x * v.x + v.y * v.y + v.z * v.z + v.w * v.w;
        bf16x4 b;
        b[0] = (__bf16)v.x; b[1] = (__bf16)v.y; b[2] = (__bf16)v.z; b[3] = (__bf16)v.w;
        *(bf16x4*)(bdst + (size_t)row * DD + (lane + 64 * c) * 4) = b;
    }
#pragma unroll
    for (int o = 32; o; o >>= 1) s += __shfl_xor(s, o);
    if (lane == 0) ndst[row] = s;
}

// ---------------------------------------------------------------------------
// Kernel 2: column sums + (last block) closed-form sigma -> invscale.
// (unchanged from round 8)
// ---------------------------------------------------------------------------
__global__ void k_colsums(const float* __restrict__ ft, const float* __restrict__ fs,
                          float* __restrict__ sumT, float* __restrict__ sumS,
                          const float* __restrict__ nt, const float* __restrict__ ns,
                          float* __restrict__ invscale, unsigned int* __restrict__ cnt) {
    int b = blockIdx.x;
    int mat = b & 1;
    int chunk = b >> 1;
    const float* src = mat ? fs : ft;
    float* dst = mat ? sumS : sumT;
    int r0 = chunk * 32;
    int c0 = threadIdx.x, c1 = threadIdx.x + 256;
    float a0 = 0.0f, a1 = 0.0f;
    for (int r = r0; r < r0 + 32; ++r) {
        a0 += src[(size_t)r * DD + c0];
        a1 += src[(size_t)r * DD + c1];
    }
    atomicAdd(&dst[c0], a0);
    atomicAdd(&dst[c1], a1);

    __shared__ int amLast;
    __threadfence();
    __syncthreads();
    if (threadIdx.x == 0) amLast = (atomicAdd(cnt, 1u) == 255u) ? 1 : 0;
    __syncthreads();
    if (!amLast) return;
    __threadfence();

    __shared__ float red[8];
    int tid = threadIdx.x;
    float s = 0.0f;
    for (int i = tid; i < NN; i += 256) s += nt[i] + ns[i];
    float d = 0.0f;
    for (int i = tid; i < DD; i += 256) d += agent_ld(&sumT[i]) * agent_ld(&sumS[i]);
#pragma unroll
    for (int o = 32; o; o >>= 1) { s += __shfl_xor(s, o); d += __shfl_xor(d, o); }
    int wid = tid >> 6, lane = tid & 63;
    if (lane == 0) { red[wid] = s; red[wid + 4] = d; }
    __syncthreads();
    if (tid == 0) {
        float S  = red[0] + red[1] + red[2] + red[3];
        float Dt = red[4] + red[5] + red[6] + red[7];
        float sigma = S / (float)NN - 2.0f * Dt / ((float)NN * (float)NN);
        invscale[0] = 1.0f / (2.0f * sigma);
    }
}

// ---------------------------------------------------------------------------
// Kernel 3: all three Grams. FULL 3x(16x32) grid (r4 dispatch shape, 1536
// blocks = 6/CU, balanced) with EARLY-EXIT triangle: sym-mode blocks with
// bj < 2*bi contain only c<r elements -> return immediately (480 of 1536).
// XCD swizzle: swz = (bid&7)*192 + bid>>3 (1536 = 8*192, bijective).
// Body identical to round 8: 256x128 tile, 8 waves (4Mx2N), wave tile 64x64,
// BK=32, double-buffered stage-ahead, conflict-free [kq][row][8] LDS.
// Sym epilogue rule: c>r -> row+col add; c==r -> row only; c<r -> skip.
// ---------------------------------------------------------------------------
__global__ __launch_bounds__(512, 4) void k_gram_all(
    const __bf16* __restrict__ T, const __bf16* __restrict__ S,
    const float* __restrict__ nt, const float* __restrict__ ns,
    const int* __restrict__ labels, const int* __restrict__ groups,
    const float* __restrict__ invscale_p,
    float* __restrict__ zTT, float* __restrict__ zSS, float* __restrict__ zTS) {

    __shared__ __bf16 As[2][4 * 256 * 8];
    __shared__ __bf16 Bs[2][4 * 128 * 8];

    int swz = ((int)blockIdx.x & 7) * 192 + ((int)blockIdx.x >> 3);
    int mode = swz >> 9;          // 512 tiles per mode
    int rem  = swz & 511;
    int bi = rem >> 5;            // 0..15
    int bj = rem & 31;            // 0..31

    // triangle early-exit: tile entirely below diagonal (max col < min row)
    if (mode != 2 && bj < 2 * bi) return;

    const __bf16* A = (mode == 1) ? S : T;
    const __bf16* B = (mode == 0) ? T : S;
    const float* nA = (mode == 1) ? ns : nt;
    const float* nB = (mode == 0) ? nt : ns;
    float* z0 = (mode == 0) ? zTT : ((mode == 1) ? zSS : zTS);
    float* z1 = zTS + NN;

    int tid = threadIdx.x;
    int i0 = bi * BM;
    int j0 = bj * BN;

    int lane = tid & 63, wid = tid >> 6;
    int wr = wid >> 1, wc = wid & 1;          // 4 x 2 wave grid
    int l15 = lane & 15, l4 = lane >> 4;

    int ra = tid & 255;
    int qa = tid >> 8;                        // 0..1
    int rb = tid & 127;
    int qb = tid >> 7;                        // 0..3
    const __bf16* gA = A + (size_t)(i0 + ra) * DD + qa * 8;   // +16 = chunk qa+2
    const __bf16* gB = B + (size_t)(j0 + rb) * DD + qb * 8;

    f32x4 acc[4][4] = {};

    load_lds16(gA,      &As[0][(size_t)tid * 8]);
    load_lds16(gA + 16, &As[0][(size_t)(tid + 512) * 8]);
    load_lds16(gB,      &Bs[0][(size_t)tid * 8]);
    __syncthreads();

#pragma unroll 2
    for (int t = 0; t < NT; ++t) {
        int b = t & 1;
        if (t < NT - 1) {
            int k0 = (t + 1) * BK;
            load_lds16(gA + k0,      &As[b ^ 1][(size_t)tid * 8]);
            load_lds16(gA + k0 + 16, &As[b ^ 1][(size_t)(tid + 512) * 8]);
            load_lds16(gB + k0,      &Bs[b ^ 1][(size_t)tid * 8]);
        }
        bf16x8 af[4], bfr[4];
#pragma unroll
        for (int im = 0; im < 4; ++im)
            af[im] = *(const bf16x8*)&As[b][((size_t)l4 * 256 + wr * 64 + im * 16 + l15) * 8];
#pragma unroll
        for (int in = 0; in < 4; ++in)
            bfr[in] = *(const bf16x8*)&Bs[b][((size_t)l4 * 128 + wc * 64 + in * 16 + l15) * 8];
#pragma unroll
        for (int im = 0; im < 4; ++im)
#pragma unroll
            for (int in = 0; in < 4; ++in)
                acc[im][in] = __builtin_amdgcn_mfma_f32_16x16x32_bf16(af[im], bfr[in], acc[im][in], 0, 0, 0);
        __syncthreads();
    }

    float inv_scale = invscale_p[0];
    int ibase = i0 + wr * 64;
    int jbase = j0 + wc * 64;
    float nBv[4];
    int labBv[4], grpBv[4];
#pragma unroll
    for (int in = 0; in < 4; ++in) {
        int j = jbase + in * 16 + l15;
        nBv[in] = nB[j];
        labBv[in] = labels[j];
        grpBv[in] = groups[j];
    }
    float cs[4] = {0.0f, 0.0f, 0.0f, 0.0f};   // sym col sums (c > r)
#pragma unroll
    for (int im = 0; im < 4; ++im) {
#pragma unroll
        for (int j = 0; j < 4; ++j) {
            int row = ibase + im * 16 + l4 * 4 + j;
            float ni = nA[row];
            int li = labels[row];
            int gi = groups[row];
            float s0 = 0.0f, s1 = 0.0f;
#pragma unroll
            for (int in = 0; in < 4; ++in) {
                float d = ni + nBv[in] - 2.0f * acc[im][in][j];
                d = fmaxf(d, 1e-12f);
                float kv = __expf(-d * inv_scale);
                bool ok = (li == labBv[in]);
                if (mode == 1) ok = ok && (gi == grpBv[in]);
                if (mode == 2) {
                    s0 += (ok && grpBv[in] == 0) ? kv : 0.0f;
                    s1 += (ok && grpBv[in] == 1) ? kv : 0.0f;
                } else {
                    int c = jbase + in * 16 + l15;
                    s0     += (ok && c >= row) ? kv : 0.0f;
                    cs[in] += (ok && c >  row) ? kv : 0.0f;
                }
            }
#pragma unroll
            for (int o = 1; o < 16; o <<= 1) {
                s0 += __shfl_xor(s0, o);
                if (mode == 2) s1 += __shfl_xor(s1, o);
            }
            if (l15 == 0) {
                atomicAdd(&z0[row], s0);
                if (mode == 2) atomicAdd(&z1[row], s1);
            }
        }
    }
    if (mode != 2) {
#pragma unroll
        for (int in = 0; in < 4; ++in) {
            cs[in] += __shfl_xor(cs[in], 16);
            cs[in] += __shfl_xor(cs[in], 32);
        }
        if (l4 == 0) {
#pragma unroll
            for (int in = 0; in < 4; ++in)
                atomicAdd(&z0[jbase + in * 16 + l15], cs[in]);
        }
    }
}

// ---------------------------------------------------------------------------
// Kernel 4: bucket per-row sums, final scalar. (unchanged from round 8)
// ---------------------------------------------------------------------------
__global__ void k_final(const int* __restrict__ labels, const int* __restrict__ groups,
                        const float* __restrict__ zTT, const float* __restrict__ zSS,
                        const float* __restrict__ zTS, float* __restrict__ out) {
    __shared__ float cnt_t[NC], cnt_s[NC * NG];
    __shared__ float nTT[NC], nSS[NC * NG], nTS[NC * NG];
    int tid = threadIdx.x;
    if (tid < NC) { cnt_t[tid] = 0.0f; nTT[tid] = 0.0f; }
    if (tid < NC * NG) { cnt_s[tid] = 0.0f; nSS[tid] = 0.0f; nTS[tid] = 0.0f; }
    __syncthreads();
    for (int i = tid; i < NN; i += 256) {
        int l = labels[i], g = groups[i];
        atomicAdd(&cnt_t[l], 1.0f);
        atomicAdd(&cnt_s[l * NG + g], 1.0f);
        atomicAdd(&nTT[l], zTT[i]);
        atomicAdd(&nSS[l * NG + g], zSS[i]);
        atomicAdd(&nTS[l * NG + 0], zTS[i]);
        atomicAdd(&nTS[l * NG + 1], zTS[NN + i]);
    }
    __syncthreads();
    if (tid == 0) {
        float total = 0.0f;
        for (int c = 0; c < NC; ++c) {
            float ntc = cnt_t[c];
            float sn = fmaxf(ntc, 1.0f);
            float meanTT = nTT[c] / (sn * sn);
            for (int g = 0; g < NG; ++g) {
                float nsg = cnt_s[c * NG + g];
                float ss = fmaxf(nsg, 1.0f);
                float meanSS = nSS[c * NG + g] / (ss * ss);
                float meanTS = nTS[c * NG + g] / (sn * ss);
                if (ntc > 0.0f && nsg > 0.0f)
                    total += meanTT + meanSS - 2.0f * meanTS;
            }
        }
        out[0] = 0.5f * total;
    }
}

// ---------------------------------------------------------------------------
// workspace layout:
// bytes [0, 4MB)      : teacher bf16 [4096][512]
// bytes [4MB, 8MB)    : student bf16 [4096][512]
// floats from 8MB (wsf):
//   +0      nt[4096]
//   +4096   ns[4096]
//   +8192   sumT[512]      <- zero region start (17412 floats)
//   +8704   sumS[512]
//   +9216   zTT[4096]
//   +13312  zSS[4096]
//   +17408  zTS[2*4096]
//   +25600  invscale[1]
//   +25601  counter_colsums (uint)
//   +25602  (spare, zeroed)
// ---------------------------------------------------------------------------
extern "C" void kernel_launch(void* const* d_in, const int* in_sizes, int n_in,
                              void* d_out, int out_size, void* d_ws, size_t ws_size,
                              hipStream_t stream) {
    const float* fs     = (const float*)d_in[0];
    const float* ft     = (const float*)d_in[1];
    const int*   groups = (const int*)d_in[2];
    const int*   labels = (const int*)d_in[3];

    __bf16* Abf = (__bf16*)d_ws;                       // teacher
    __bf16* Bbf = (__bf16*)d_ws + (size_t)NN * DD;     // student
    float* wsf  = (float*)((char*)d_ws + (size_t)2 * NN * DD * sizeof(__bf16));
    float* nt   = wsf;
    float* ns   = wsf + 4096;
    float* sumT = wsf + 8192;
    float* sumS = wsf + 8704;
    float* zTT  = wsf + 9216;
    float* zSS  = wsf + 13312;
    float* zTS  = wsf + 17408;
    float* invs = wsf + 25600;
    unsigned int* cntC = (unsigned int*)(wsf + 25601);

    k_prep<<<2048, 256, 0, stream>>>(ft, fs, Abf, Bbf, nt, ns, wsf + 8192);
    k_colsums<<<256, 256, 0, stream>>>(ft, fs, sumT, sumS, nt, ns, invs, cntC);
    k_gram_all<<<NTILES, 512, 0, stream>>>(Abf, Bbf, nt, ns, labels, groups,
                                           invs, zTT, zSS, zTS);
    k_final<<<1, 256, 0, stream>>>(labels, groups, zTT, zSS, zTS, (float*)d_out);
}

// Round 11
// 193.546 us; speedup vs baseline: 1.2422x; 1.0999x over previous
//
#include <hip/hip_runtime.h>
#include <math.h>

#define NN 4096
#define DD 512
#define NC 10
#define NG 2

#define BM 256
#define BN 128
#define BK 32
#define NT (DD / BK)     // 16 K-steps
#define NBLK 512         // persistent: 64 slots x 8 XCDs; 1056 tiles total

typedef __bf16 bf16x8 __attribute__((ext_vector_type(8)));
typedef __bf16 bf16x4 __attribute__((ext_vector_type(4)));
typedef float f32x4 __attribute__((ext_vector_type(4)));

__device__ __forceinline__ void load_lds16(const __bf16* g, __bf16* l) {
    __builtin_amdgcn_global_load_lds((const __attribute__((address_space(1))) void*)g,
                                     (__attribute__((address_space(3))) void*)l, 16, 0, 0);
}

__device__ __forceinline__ float agent_ld(const float* p) {
    return __hip_atomic_load(p, __ATOMIC_RELAXED, __HIP_MEMORY_SCOPE_AGENT);
}

// ---------------------------------------------------------------------------
// Kernel 1: fused fp32->bf16 convert + per-row squared norms (fp32 exact)
// + zeroing of the accumulator region. (unchanged from round 8)
// ---------------------------------------------------------------------------
__global__ void k_prep(const float* __restrict__ ft, const float* __restrict__ fs,
                       __bf16* __restrict__ at, __bf16* __restrict__ as_,
                       float* __restrict__ nt, float* __restrict__ ns,
                       float* __restrict__ zero_base) {
    if (blockIdx.x < 69) {
        int idx = blockIdx.x * 256 + threadIdx.x;
        if (idx < 17412) zero_base[idx] = 0.0f;
    }
    int wid  = threadIdx.x >> 6;
    int lane = threadIdx.x & 63;
    int r = blockIdx.x * 4 + wid;
    const float* src; __bf16* bdst; float* ndst; int row;
    if (r < NN) { src = ft; bdst = at;  ndst = nt; row = r; }
    else        { src = fs; bdst = as_; ndst = ns; row = r - NN; }
    const float4* p = (const float4*)(src + (size_t)row * DD);
    float s = 0.0f;
#pragma unroll
    for (int c = 0; c < 2; ++c) {
        float4 v = p[lane + 64 * c];
        s += v.x * v.x + v.y * v.y + v.z * v.z + v.w * v.w;
        bf16x4 b;
        b[0] = (__bf16)v.x; b[1] = (__bf16)v.y; b[2] = (__bf16)v.z; b[3] = (__bf16)v.w;
        *(bf16x4*)(bdst + (size_t)row * DD + (lane + 64 * c) * 4) = b;
    }
#pragma unroll
    for (int o = 32; o; o >>= 1) s += __shfl_xor(s, o);
    if (lane == 0) ndst[row] = s;
}

// ---------------------------------------------------------------------------
// Kernel 2: column sums + (last block) closed-form sigma -> invscale.
// (unchanged from round 8)
// ---------------------------------------------------------------------------
__global__ void k_colsums(const float* __restrict__ ft, const float* __restrict__ fs,
                          float* __restrict__ sumT, float* __restrict__ sumS,
                          const float* __restrict__ nt, const float* __restrict__ ns,
                          float* __restrict__ invscale, unsigned int* __restrict__ cnt) {
    int b = blockIdx.x;
    int mat = b & 1;
    int chunk = b >> 1;
    const float* src = mat ? fs : ft;
    float* dst = mat ? sumS : sumT;
    int r0 = chunk * 32;
    int c0 = threadIdx.x, c1 = threadIdx.x + 256;
    float a0 = 0.0f, a1 = 0.0f;
    for (int r = r0; r < r0 + 32; ++r) {
        a0 += src[(size_t)r * DD + c0];
        a1 += src[(size_t)r * DD + c1];
    }
    atomicAdd(&dst[c0], a0);
    atomicAdd(&dst[c1], a1);

    __shared__ int amLast;
    __threadfence();
    __syncthreads();
    if (threadIdx.x == 0) amLast = (atomicAdd(cnt, 1u) == 255u) ? 1 : 0;
    __syncthreads();
    if (!amLast) return;
    __threadfence();

    __shared__ float red[8];
    int tid = threadIdx.x;
    float s = 0.0f;
    for (int i = tid; i < NN; i += 256) s += nt[i] + ns[i];
    float d = 0.0f;
    for (int i = tid; i < DD; i += 256) d += agent_ld(&sumT[i]) * agent_ld(&sumS[i]);
#pragma unroll
    for (int o = 32; o; o >>= 1) { s += __shfl_xor(s, o); d += __shfl_xor(d, o); }
    int wid = tid >> 6, lane = tid & 63;
    if (lane == 0) { red[wid] = s; red[wid + 4] = d; }
    __syncthreads();
    if (tid == 0) {
        float S  = red[0] + red[1] + red[2] + red[3];
        float Dt = red[4] + red[5] + red[6] + red[7];
        float sigma = S / (float)NN - 2.0f * Dt / ((float)NN * (float)NN);
        invscale[0] = 1.0f / (2.0f * sigma);
    }
}

// ---------------------------------------------------------------------------
// Kernel 3: all three Grams, PERSISTENT 512 blocks (2/CU = VGPR residency).
// Block b = (xcd x = b&7, slot s = b>>3) processes tiles x*132 + s + 64k,
// k = 0,1(,2 for s<4) -> same 1056-tile space and XCD-chunk locality as r8,
// but no dispatch tail: every CU holds 2 blocks until the final ~1 tile.
// Tile decode (r8): [0,272) TT triangle (bj>=2bi), [272,544) SS, [544,1056) TS.
// Body per tile: IDENTICAL to round 8 (best measured): 256x128 tile, 8 waves
// (4Mx2N), wave tile 64x64, BK=32, double-buffered stage-ahead,
// conflict-free [kq][row][8] LDS; sym epilogue c>r -> row+col, c==r -> row.
// ---------------------------------------------------------------------------
__global__ __launch_bounds__(512, 4) void k_gram_all(
    const __bf16* __restrict__ T, const __bf16* __restrict__ S,
    const float* __restrict__ nt, const float* __restrict__ ns,
    const int* __restrict__ labels, const int* __restrict__ groups,
    const float* __restrict__ invscale_p,
    float* __restrict__ zTT, float* __restrict__ zSS, float* __restrict__ zTS) {

    __shared__ __bf16 As[2][4 * 256 * 8];
    __shared__ __bf16 Bs[2][4 * 128 * 8];

    int x = (int)blockIdx.x & 7;
    int slot = (int)blockIdx.x >> 3;          // 0..63
    float inv_scale = invscale_p[0];

    int tid = threadIdx.x;
    int lane = tid & 63, wid = tid >> 6;
    int wr = wid >> 1, wc = wid & 1;          // 4 x 2 wave grid
    int l15 = lane & 15, l4 = lane >> 4;
    int ra = tid & 255;
    int qa = tid >> 8;                        // 0..1
    int rb = tid & 127;

    for (int rep = 0;; ++rep) {
        int idx = slot + 64 * rep;
        if (idx >= 132) break;
        int swz = x * 132 + idx;

        int mode, bi, bj;
        if (swz < 544) {
            mode = (swz < 272) ? 0 : 1;
            int kk = (swz < 272) ? swz : swz - 272;
            int t = 0;
            while (kk >= 32 - 2 * t) { kk -= 32 - 2 * t; ++t; }   // <=16 iters
            bi = t; bj = 2 * t + kk;
        } else {
            mode = 2;
            int kk = swz - 544;
            bi = kk >> 5; bj = kk & 31;
        }

        const __bf16* A = (mode == 1) ? S : T;
        const __bf16* B = (mode == 0) ? T : S;
        const float* nA = (mode == 1) ? ns : nt;
        const float* nB = (mode == 0) ? nt : ns;
        float* z0 = (mode == 0) ? zTT : ((mode == 1) ? zSS : zTS);
        float* z1 = zTS + NN;

        int i0 = bi * BM;
        int j0 = bj * BN;
        const __bf16* gA = A + (size_t)(i0 + ra) * DD + qa * 8;   // +16 = chunk qa+2
        const __bf16* gB = B + (size_t)(j0 + rb) * DD + (tid >> 7) * 8;

        f32x4 acc[4][4] = {};

        load_lds16(gA,      &As[0][(size_t)tid * 8]);
        load_lds16(gA + 16, &As[0][(size_t)(tid + 512) * 8]);
        load_lds16(gB,      &Bs[0][(size_t)tid * 8]);
        __syncthreads();

#pragma unroll 2
        for (int t = 0; t < NT; ++t) {
            int b = t & 1;
            if (t < NT - 1) {
                int k0 = (t + 1) * BK;
                load_lds16(gA + k0,      &As[b ^ 1][(size_t)tid * 8]);
                load_lds16(gA + k0 + 16, &As[b ^ 1][(size_t)(tid + 512) * 8]);
                load_lds16(gB + k0,      &Bs[b ^ 1][(size_t)tid * 8]);
            }
            bf16x8 af[4], bfr[4];
#pragma unroll
            for (int im = 0; im < 4; ++im)
                af[im] = *(const bf16x8*)&As[b][((size_t)l4 * 256 + wr * 64 + im * 16 + l15) * 8];
#pragma unroll
            for (int in = 0; in < 4; ++in)
                bfr[in] = *(const bf16x8*)&Bs[b][((size_t)l4 * 128 + wc * 64 + in * 16 + l15) * 8];
#pragma unroll
            for (int im = 0; im < 4; ++im)
#pragma unroll
                for (int in = 0; in < 4; ++in)
                    acc[im][in] = __builtin_amdgcn_mfma_f32_16x16x32_bf16(af[im], bfr[in], acc[im][in], 0, 0, 0);
            __syncthreads();
        }

        // epilogue: D = nA + nB - 2*dot -> exp -> predicate -> row/col sums
        int ibase = i0 + wr * 64;
        int jbase = j0 + wc * 64;
        float nBv[4];
        int labBv[4], grpBv[4];
#pragma unroll
        for (int in = 0; in < 4; ++in) {
            int j = jbase + in * 16 + l15;
            nBv[in] = nB[j];
            labBv[in] = labels[j];
            grpBv[in] = groups[j];
        }
        float cs[4] = {0.0f, 0.0f, 0.0f, 0.0f};   // sym col sums (c > r)
#pragma unroll
        for (int im = 0; im < 4; ++im) {
#pragma unroll
            for (int j = 0; j < 4; ++j) {
                int row = ibase + im * 16 + l4 * 4 + j;
                float ni = nA[row];
                int li = labels[row];
                int gi = groups[row];
                float s0 = 0.0f, s1 = 0.0f;
#pragma unroll
                for (int in = 0; in < 4; ++in) {
                    float d = ni + nBv[in] - 2.0f * acc[im][in][j];
                    d = fmaxf(d, 1e-12f);
                    float kv = __expf(-d * inv_scale);
                    bool ok = (li == labBv[in]);
                    if (mode == 1) ok = ok && (gi == grpBv[in]);
                    if (mode == 2) {
                        s0 += (ok && grpBv[in] == 0) ? kv : 0.0f;
                        s1 += (ok && grpBv[in] == 1) ? kv : 0.0f;
                    } else {
                        int c = jbase + in * 16 + l15;
                        s0     += (ok && c >= row) ? kv : 0.0f;
                        cs[in] += (ok && c >  row) ? kv : 0.0f;
                    }
                }
#pragma unroll
                for (int o = 1; o < 16; o <<= 1) {
                    s0 += __shfl_xor(s0, o);
                    if (mode == 2) s1 += __shfl_xor(s1, o);
                }
                if (l15 == 0) {
                    atomicAdd(&z0[row], s0);
                    if (mode == 2) atomicAdd(&z1[row], s1);
                }
            }
        }
        if (mode != 2) {
#pragma unroll
            for (int in = 0; in < 4; ++in) {
                cs[in] += __shfl_xor(cs[in], 16);
                cs[in] += __shfl_xor(cs[in], 32);
            }
            if (l4 == 0) {
#pragma unroll
                for (int in = 0; in < 4; ++in)
                    atomicAdd(&z0[jbase + in * 16 + l15], cs[in]);
            }
        }
        // LDS safe to reuse: all ds_reads completed before the last K-step sync;
        // epilogue touches only registers + global.
    }
}

// ---------------------------------------------------------------------------
// Kernel 4: bucket per-row sums, final scalar. (unchanged from round 8)
// ---------------------------------------------------------------------------
__global__ void k_final(const int* __restrict__ labels, const int* __restrict__ groups,
                        const float* __restrict__ zTT, const float* __restrict__ zSS,
                        const float* __restrict__ zTS, float* __restrict__ out) {
    __shared__ float cnt_t[NC], cnt_s[NC * NG];
    __shared__ float nTT[NC], nSS[NC * NG], nTS[NC * NG];
    int tid = threadIdx.x;
    if (tid < NC) { cnt_t[tid] = 0.0f; nTT[tid] = 0.0f; }
    if (tid < NC * NG) { cnt_s[tid] = 0.0f; nSS[tid] = 0.0f; nTS[tid] = 0.0f; }
    __syncthreads();
    for (int i = tid; i < NN; i += 256) {
        int l = labels[i], g = groups[i];
        atomicAdd(&cnt_t[l], 1.0f);
        atomicAdd(&cnt_s[l * NG + g], 1.0f);
        atomicAdd(&nTT[l], zTT[i]);
        atomicAdd(&nSS[l * NG + g], zSS[i]);
        atomicAdd(&nTS[l * NG + 0], zTS[i]);
        atomicAdd(&nTS[l * NG + 1], zTS[NN + i]);
    }
    __syncthreads();
    if (tid == 0) {
        float total = 0.0f;
        for (int c = 0; c < NC; ++c) {
            float ntc = cnt_t[c];
            float sn = fmaxf(ntc, 1.0f);
            float meanTT = nTT[c] / (sn * sn);
            for (int g = 0; g < NG; ++g) {
                float nsg = cnt_s[c * NG + g];
                float ss = fmaxf(nsg, 1.0f);
                float meanSS = nSS[c * NG + g] / (ss * ss);
                float meanTS = nTS[c * NG + g] / (sn * ss);
                if (ntc > 0.0f && nsg > 0.0f)
                    total += meanTT + meanSS - 2.0f * meanTS;
            }
        }
        out[0] = 0.5f * total;
    }
}

// ---------------------------------------------------------------------------
// workspace layout:
// bytes [0, 4MB)      : teacher bf16 [4096][512]
// bytes [4MB, 8MB)    : student bf16 [4096][512]
// floats from 8MB (wsf):
//   +0      nt[4096]
//   +4096   ns[4096]
//   +8192   sumT[512]      <- zero region start (17412 floats)
//   +8704   sumS[512]
//   +9216   zTT[4096]
//   +13312  zSS[4096]
//   +17408  zTS[2*4096]
//   +25600  invscale[1]
//   +25601  counter_colsums (uint)
//   +25602  (spare, zeroed)
// ---------------------------------------------------------------------------
extern "C" void kernel_launch(void* const* d_in, const int* in_sizes, int n_in,
                              void* d_out, int out_size, void* d_ws, size_t ws_size,
                              hipStream_t stream) {
    const float* fs     = (const float*)d_in[0];
    const float* ft     = (const float*)d_in[1];
    const int*   groups = (const int*)d_in[2];
    const int*   labels = (const int*)d_in[3];

    __bf16* Abf = (__bf16*)d_ws;                       // teacher
    __bf16* Bbf = (__bf16*)d_ws + (size_t)NN * DD;     // student
    float* wsf  = (float*)((char*)d_ws + (size_t)2 * NN * DD * sizeof(__bf16));
    float* nt   = wsf;
    float* ns   = wsf + 4096;
    float* sumT = wsf + 8192;
    float* sumS = wsf + 8704;
    float* zTT  = wsf + 9216;
    float* zSS  = wsf + 13312;
    float* zTS  = wsf + 17408;
    float* invs = wsf + 25600;
    unsigned int* cntC = (unsigned int*)(wsf + 25601);

    k_prep<<<2048, 256, 0, stream>>>(ft, fs, Abf, Bbf, nt, ns, wsf + 8192);
    k_colsums<<<256, 256, 0, stream>>>(ft, fs, sumT, sumS, nt, ns, invs, cntC);
    k_gram_all<<<NBLK, 512, 0, stream>>>(Abf, Bbf, nt, ns, labels, groups,
                                         invs, zTT, zSS, zTS);
    k_final<<<1, 256, 0, stream>>>(labels, groups, zTT, zSS, zTS, (float*)d_out);
}